// Round 17
// baseline (284.665 us; speedup 1.0000x reference)
//
#include <hip/hip_runtime.h>

#define THRF 0.05f

// ---------------------------------------------------------------------------
// Fused pre-pass: latency encode + weight transposes + workspace zeroing
// (replaces the separate hipMemsetAsync dispatch; grid-stride coalesced
// stores zero z1p+z2p+zbuf = 1003552 dwords before the atomicOr stages).
//  w1T[k*32+oc]          = W1[oc*9+k]
//  w2T[kk*1024+ic*32+oc] = W2[oc*288+ic*9+kk]
//  WdT[f*64+o]           = Wd[o*1568+f]
// ---------------------------------------------------------------------------
__global__ void k_pre(const float* __restrict__ x, const float* __restrict__ W1,
                      const float* __restrict__ W2, const float* __restrict__ Wd,
                      unsigned* __restrict__ mIn, float* __restrict__ w1T,
                      float* __restrict__ w2T, float* __restrict__ WdT,
                      unsigned* __restrict__ zr) {
  int i = blockIdx.x * blockDim.x + threadIdx.x;
  if (i >= 100352) return;
  // zero z1p + z2p + zbuf (1003552 dwords), coalesced grid-stride
  for (int j = i; j < 1003552; j += 100352) zr[j] = 0u;
  float xv = x[i];
  float st = fminf(19.0f * (1.0f - xv), 19.0f * 0.95f);
  int t = (int)rintf(st);
  t = t < 0 ? 0 : (t > 19 ? 19 : t);
  mIn[i] = (xv >= THRF) ? (1u << t) : 0u;
  { int o = i / 1568, f = i % 1568; WdT[f * 64 + o] = Wd[i]; }
  if (i < 9216) {
    int oc = i / 288, k = i % 288, ic = k / 9, kk = k % 9;
    w2T[kk * 1024 + ic * 32 + oc] = W2[i];
  }
  if (i < 288) { int oc = i / 9, k = i % 9; w1T[k * 32 + oc] = W1[i]; }
}

// ---------------------------------------------------------------------------
// Stage 1: conv1(3x3 SAME, 1->32) + LIF + maxpool, lane-parallel over t.
// (unchanged from passing rounds 6-16)
// ---------------------------------------------------------------------------
__global__ __launch_bounds__(128) void k_stage1M(const unsigned* __restrict__ mIn,
                                                 const float* __restrict__ w1T,
                                                 unsigned* __restrict__ z1p) {
  __shared__ float xp[2][20 * 66];
  int lane = threadIdx.x & 63;
  int wid  = threadIdx.x >> 6;
  int gw   = blockIdx.x * 2 + wid;     // wave index
  int pA = 2 * gw, pB = 2 * gw + 1;    // pre-pool pixel = b*784 + y*28 + x
  int bA = pA / 784, rA = pA % 784, yA = rA / 28, xA = rA % 28;
  int bB = pB / 784, rB = pB % 784, yB = rB / 28, xB = rB % 28;
  int tl = lane & 31, hiB = lane >> 5;

  unsigned mA[9], mB[9];
  for (int ky = 0; ky < 3; ++ky) {
    for (int kx = 0; kx < 3; ++kx) {
      int k = ky * 3 + kx;
      int ya = yA - 1 + ky, xa = xA - 1 + kx;
      int yb = yB - 1 + ky, xb = xB - 1 + kx;
      mA[k] = (ya >= 0 && ya < 28 && xa >= 0 && xa < 28) ? mIn[bA * 784 + ya * 28 + xa] : 0u;
      mB[k] = (yb >= 0 && yb < 28 && xb >= 0 && xb < 28) ? mIn[bB * 784 + yb * 28 + xb] : 0u;
    }
  }

  float acc[32];
#pragma unroll
  for (int o = 0; o < 32; ++o) acc[o] = 0.0f;

  for (int k = 0; k < 9; ++k) {
    unsigned long long m64 = ((unsigned long long)mB[k] << 32) | (unsigned long long)mA[k];
    float bitf = (float)((m64 >> lane) & 1ull);
    const float* wrow = w1T + k * 32;
#pragma unroll
    for (int oc = 0; oc < 32; ++oc)
      acc[oc] = fmaf(wrow[oc], bitf, acc[oc]);
  }

  if (tl < 20) {
#pragma unroll
    for (int oc = 0; oc < 32; ++oc)
      xp[wid][tl * 66 + hiB * 32 + oc] = acc[oc];
  }
  __syncthreads();

  float v = 0.0f;
  int   r = 0;
  unsigned zm = 0u;
#pragma unroll
  for (int t = 0; t < 20; ++t) {
    float c = xp[wid][t * 66 + lane];
    v += c;
    bool z = (v > THRF) && (r == 0);
    if (z) { v -= THRF; r = 3; } else if (r > 0) --r;
    if (z) zm |= 1u << t;
  }
  int p = hiB ? pB : pA;
  int b = p / 784, rr = p % 784, y = rr / 28, x = rr % 28;
  atomicOr(&z1p[((b * 14 + (y >> 1)) * 14 + (x >> 1)) * 32 + tl], zm);
}

// ---------------------------------------------------------------------------
// Stage 2: conv2 + LIF + maxpool — round-9 k_stage2E structure (measured
// best of 8 variants) with ONE isolated change: the per-ic mask select
// (2 cndmask + shr) is replaced by the round-6-proven SALU 64-bit pack
// B = s0|s1<<20|s2<<40 (SGPR ops, off the VALU pipe) + per-lane
// shr64+and+cvt. Lanes 60-63 read pack bits 60..63 == 0 -> bitf=0 ->
// discarded in epilogue. Accumulation per (neuron,t): ascending (ky,kx,ic),
// ic innermost; bit=0 terms add +0.0 (exact no-op) — bit-identical.
// ---------------------------------------------------------------------------
__global__ __launch_bounds__(256) void k_stage2E(const unsigned* __restrict__ z1p,
                                                 const float* __restrict__ wT2,
                                                 const unsigned* __restrict__ zbuf,
                                                 unsigned* __restrict__ z2p) {
  __shared__ float xp[4][20 * 97];
  int lane = threadIdx.x & 63;
  int wid  = threadIdx.x >> 6;
  int gw   = blockIdx.x * 4 + wid;             // wave index
  int q0 = 3 * gw, q1 = q0 + 1, q2 = q0 + 2;   // pixels: b*196 + y*14 + x
  bool vq0 = q0 < 25088, vq1 = q1 < 25088, vq2 = q2 < 25088;
  int b0 = q0 / 196, r0 = q0 % 196, y0 = r0 / 14, x0 = r0 % 14;
  int b1 = q1 / 196, r1 = q1 % 196, y1 = r1 / 14, x1 = r1 % 14;
  int b2 = q2 / 196, r2 = q2 % 196, y2 = r2 / 14, x2 = r2 % 14;

  int  li = lane & 31;
  bool lo = lane < 32;
  int  p  = lane / 20;             // 0..3 (p==3 idle in epilogue)
  int  tl = lane - p * 20;

  float acc[32];
#pragma unroll
  for (int o = 0; o < 32; ++o) acc[o] = 0.0f;

  // cell pointer computation (uniform per wave)
  auto cptr = [&](int ky, int kx, const unsigned*& c0, const unsigned*& c1,
                  const unsigned*& c2) {
    int y0k = y0 - 1 + ky, y1k = y1 - 1 + ky, y2k = y2 - 1 + ky;
    int x0k = x0 - 1 + kx, x1k = x1 - 1 + kx, x2k = x2 - 1 + kx;
    bool ok0 = vq0 && y0k >= 0 && y0k < 14 && x0k >= 0 && x0k < 14;
    bool ok1 = vq1 && y1k >= 0 && y1k < 14 && x1k >= 0 && x1k < 14;
    bool ok2 = vq2 && y2k >= 0 && y2k < 14 && x2k >= 0 && x2k < 14;
    c0 = ok0 ? (z1p + ((b0 * 14 + y0k) * 14 + x0k) * 32) : zbuf;
    c1 = ok1 ? (z1p + ((b1 * 14 + y1k) * 14 + x1k) * 32) : zbuf;
    c2 = ok2 ? (z1p + ((b2 * 14 + y2k) * 14 + x2k) * 32) : zbuf;
  };

  const unsigned *c0, *c1, *c2;
  cptr(0, 0, c0, c1, c2);
  unsigned va = (lo ? c0 : c1)[li];   // lanes 0-31: c0[li], 32-63: c1[li]
  unsigned vb = c2[li];

  for (int ky = 0; ky < 3; ++ky) {
    for (int kx = 0; kx < 3; ++kx) {
      // prefetch next cell
      unsigned va_n = 0u, vb_n = 0u;
      int nkx = kx + 1, nky = ky;
      if (nkx == 3) { nkx = 0; nky = ky + 1; }
      if (nky < 3) {
        const unsigned *n0, *n1, *n2;
        cptr(nky, nkx, n0, n1, n2);
        va_n = (lo ? n0 : n1)[li];
        vb_n = n2[li];
      }
      const float* wc = wT2 + (ky * 3 + kx) * 1024;
#pragma unroll 4
      for (int ic = 0; ic < 32; ++ic) {
        unsigned s0 = (unsigned)__builtin_amdgcn_readlane((int)va, ic);
        unsigned s1 = (unsigned)__builtin_amdgcn_readlane((int)va, 32 + ic);
        unsigned s2 = (unsigned)__builtin_amdgcn_readlane((int)vb, ic);
        unsigned long long B = (unsigned long long)s0 |
                               ((unsigned long long)s1 << 20) |
                               ((unsigned long long)s2 << 40);
        float bitf = (float)((B >> lane) & 1ull);   // lane = p*20 + t
        const float* wrow = wc + ic * 32;
#pragma unroll
        for (int oc = 0; oc < 32; ++oc)
          acc[oc] = fmaf(wrow[oc], bitf, acc[oc]);
      }
      va = va_n; vb = vb_n;
    }
  }

  if (p < 3) {
#pragma unroll
    for (int oc = 0; oc < 32; ++oc)
      xp[wid][tl * 97 + p * 32 + oc] = acc[oc];
  }
  __syncthreads();

  for (int pass = 0; pass < 2; ++pass) {
    int n = lane + 64 * pass;
    if (n < 96) {
      int pp = n >> 5;
      int oc = n & 31;
      int q  = q0 + pp;
      if (q < 25088) {
        float v = 0.0f;
        int   r = 0;
        unsigned zm = 0u;
#pragma unroll
        for (int t = 0; t < 20; ++t) {
          float c = xp[wid][t * 97 + n];
          v += c;
          bool z = (v > THRF) && (r == 0);
          if (z) { v -= THRF; r = 3; } else if (r > 0) --r;
          if (z) zm |= 1u << t;
        }
        int b = q / 196, rr = q % 196, y = rr / 14, x = rr % 14;
        atomicOr(&z2p[b * 1568 + oc * 49 + (y >> 1) * 7 + (x >> 1)], zm);
      }
    }
  }
}

// ---------------------------------------------------------------------------
// Stage 3: dense currents + OUTPUT LIF fused (unchanged from rounds 9-16).
// ---------------------------------------------------------------------------
__global__ __launch_bounds__(256) void k_denseF(const unsigned* __restrict__ z2p,
                                                const float* __restrict__ WdT,
                                                float* __restrict__ out) {
  int lane = threadIdx.x & 63;
  int wid  = threadIdx.x >> 6;
  int gw   = blockIdx.x * 4 + wid;     // b*22 + og
  if (gw >= 128 * 22) return;
  int b  = gw / 22, og = gw % 22;
  int p  = lane / 20;                  // 0..3 (p==3 idle)
  int t  = lane - p * 20;
  int o  = og * 3 + p;
  bool live = (p < 3) && (o < 64);
  int osafe = live ? o : 63;
  const unsigned* zb = z2p + b * 1568;

  unsigned mA[16], mB[16];
  float    wA[16], wB[16];
#pragma unroll
  for (int u = 0; u < 16; ++u) { mA[u] = zb[u]; wA[u] = WdT[u * 64 + osafe]; }

  float acc = 0.0f;
  for (int f0 = 0; f0 < 1568; f0 += 32) {   // 1568 = 32*49
#pragma unroll
    for (int u = 0; u < 16; ++u) {
      int fn = f0 + 16 + u;
      mB[u] = zb[fn]; wB[u] = WdT[fn * 64 + osafe];
    }
#pragma unroll
    for (int u = 0; u < 16; ++u) {
      float bitf = (float)((mA[u] >> t) & 1u);
      acc = fmaf(wA[u], bitf, acc);
    }
    if (f0 + 32 < 1568) {
#pragma unroll
      for (int u = 0; u < 16; ++u) {
        int fn = f0 + 32 + u;
        mA[u] = zb[fn]; wA[u] = WdT[fn * 64 + osafe];
      }
    }
#pragma unroll
    for (int u = 0; u < 16; ++u) {
      float bitf = (float)((mB[u] >> t) & 1u);
      acc = fmaf(wB[u], bitf, acc);
    }
  }

  float v = 0.0f;
  int   r = 0;
  unsigned zm = 0u;
#pragma unroll
  for (int tt = 0; tt < 20; ++tt) {
    float c = __shfl(acc, p * 20 + tt, 64);  // p==3 lanes: garbage, discarded
    v += c;
    bool z = (v > THRF) && (r == 0);
    if (z) { v -= THRF; r = 3; } else if (r > 0) --r;
    if (z) zm |= 1u << tt;
  }
  if (live) out[(b * 20 + t) * 64 + o] = ((zm >> t) & 1u) ? 1.0f : 0.0f;
}

extern "C" void kernel_launch(void* const* d_in, const int* in_sizes, int n_in,
                              void* d_out, int out_size, void* d_ws, size_t ws_size,
                              hipStream_t stream) {
  const float* x  = (const float*)d_in[0];  // [128,1,28,28]
  const float* W1 = (const float*)d_in[1];  // [32,1,3,3]
  const float* W2 = (const float*)d_in[2];  // [32,32,3,3]
  const float* Wd = (const float*)d_in[3];  // [64,1568]
  float* out = (float*)d_out;               // [128,20,64]

  char* ws = (char*)d_ws;
  unsigned* mIn  = (unsigned*)ws;                      // 401408 B (dead after stage1)
  unsigned* z1p  = (unsigned*)(ws + 655360);           // 3211264 B (zeroed by k_pre)
  unsigned* z2p  = (unsigned*)(ws + 3866624);          // 802816 B (zeroed by k_pre)
  unsigned* zbuf = (unsigned*)(ws + 4669440);          // 128 B zeros (zeroed by k_pre)
  float*    w1T  = (float*)(ws + 4669568);             // 1152 B
  float*    w2T  = (float*)(ws + 4670720);             // 36864 B
  float*    WdT  = (float*)(ws + 4707584);             // 401408 B

  k_pre<<<dim3(392), dim3(256), 0, stream>>>(x, W1, W2, Wd, mIn, w1T, w2T, WdT, z1p);
  k_stage1M<<<dim3(25088), dim3(128), 0, stream>>>(mIn, w1T, z1p);
  k_stage2E<<<dim3(2091), dim3(256), 0, stream>>>(z1p, w2T, zbuf, z2p);
  k_denseF<<<dim3(704), dim3(256), 0, stream>>>(z2p, WdT, out);
}

// Round 18
// 276.602 us; speedup vs baseline: 1.0291x; 1.0291x over previous
//
#include <hip/hip_runtime.h>

#define THRF 0.05f

// ---------------------------------------------------------------------------
// Fused pre-pass: latency encode + weight transposes + workspace zeroing
// (zeroing fused here saved ~15 us vs separate hipMemsetAsync — round 17).
//  w1T[k*32+oc]          = W1[oc*9+k]
//  w2T[kk*1024+ic*32+oc] = W2[oc*288+ic*9+kk]
//  WdT[f*64+o]           = Wd[o*1568+f]
// ---------------------------------------------------------------------------
__global__ void k_pre(const float* __restrict__ x, const float* __restrict__ W1,
                      const float* __restrict__ W2, const float* __restrict__ Wd,
                      unsigned* __restrict__ mIn, float* __restrict__ w1T,
                      float* __restrict__ w2T, float* __restrict__ WdT,
                      unsigned* __restrict__ zr) {
  int i = blockIdx.x * blockDim.x + threadIdx.x;
  if (i >= 100352) return;
  // zero z1p + z2p + zbuf (1003552 dwords), coalesced grid-stride
  for (int j = i; j < 1003552; j += 100352) zr[j] = 0u;
  float xv = x[i];
  float st = fminf(19.0f * (1.0f - xv), 19.0f * 0.95f);
  int t = (int)rintf(st);
  t = t < 0 ? 0 : (t > 19 ? 19 : t);
  mIn[i] = (xv >= THRF) ? (1u << t) : 0u;
  { int o = i / 1568, f = i % 1568; WdT[f * 64 + o] = Wd[i]; }
  if (i < 9216) {
    int oc = i / 288, k = i % 288, ic = k / 9, kk = k % 9;
    w2T[kk * 1024 + ic * 32 + oc] = W2[i];
  }
  if (i < 288) { int oc = i / 9, k = i % 9; w1T[k * 32 + oc] = W1[i]; }
}

// ---------------------------------------------------------------------------
// Stage 1: conv1(3x3 SAME, 1->32) + LIF + maxpool, lane-parallel over t.
// (unchanged from passing rounds 6-17)
// ---------------------------------------------------------------------------
__global__ __launch_bounds__(128) void k_stage1M(const unsigned* __restrict__ mIn,
                                                 const float* __restrict__ w1T,
                                                 unsigned* __restrict__ z1p) {
  __shared__ float xp[2][20 * 66];
  int lane = threadIdx.x & 63;
  int wid  = threadIdx.x >> 6;
  int gw   = blockIdx.x * 2 + wid;     // wave index
  int pA = 2 * gw, pB = 2 * gw + 1;    // pre-pool pixel = b*784 + y*28 + x
  int bA = pA / 784, rA = pA % 784, yA = rA / 28, xA = rA % 28;
  int bB = pB / 784, rB = pB % 784, yB = rB / 28, xB = rB % 28;
  int tl = lane & 31, hiB = lane >> 5;

  unsigned mA[9], mB[9];
  for (int ky = 0; ky < 3; ++ky) {
    for (int kx = 0; kx < 3; ++kx) {
      int k = ky * 3 + kx;
      int ya = yA - 1 + ky, xa = xA - 1 + kx;
      int yb = yB - 1 + ky, xb = xB - 1 + kx;
      mA[k] = (ya >= 0 && ya < 28 && xa >= 0 && xa < 28) ? mIn[bA * 784 + ya * 28 + xa] : 0u;
      mB[k] = (yb >= 0 && yb < 28 && xb >= 0 && xb < 28) ? mIn[bB * 784 + yb * 28 + xb] : 0u;
    }
  }

  float acc[32];
#pragma unroll
  for (int o = 0; o < 32; ++o) acc[o] = 0.0f;

  for (int k = 0; k < 9; ++k) {
    unsigned long long m64 = ((unsigned long long)mB[k] << 32) | (unsigned long long)mA[k];
    float bitf = (float)((m64 >> lane) & 1ull);
    const float* wrow = w1T + k * 32;
#pragma unroll
    for (int oc = 0; oc < 32; ++oc)
      acc[oc] = fmaf(wrow[oc], bitf, acc[oc]);
  }

  if (tl < 20) {
#pragma unroll
    for (int oc = 0; oc < 32; ++oc)
      xp[wid][tl * 66 + hiB * 32 + oc] = acc[oc];
  }
  __syncthreads();

  float v = 0.0f;
  int   r = 0;
  unsigned zm = 0u;
#pragma unroll
  for (int t = 0; t < 20; ++t) {
    float c = xp[wid][t * 66 + lane];
    v += c;
    bool z = (v > THRF) && (r == 0);
    if (z) { v -= THRF; r = 3; } else if (r > 0) --r;
    if (z) zm |= 1u << t;
  }
  int p = hiB ? pB : pA;
  int b = p / 784, rr = p % 784, y = rr / 28, x = rr % 28;
  atomicOr(&z1p[((b * 14 + (y >> 1)) * 14 + (x >> 1)) * 32 + tl], zm);
}

// ---------------------------------------------------------------------------
// Stage 2: conv2 + LIF + maxpool — ROUND-9/16 k_stage2E VERBATIM (measured
// best across 9 variants: 166-171 us; round-17's SALU-pack variant regressed
// to 192 via v_lshrrev_b64 on the critical path — reverted). 3 pixels/wave,
// 4 waves/block; vector-path mask loads prefetched one cell ahead; per ic:
// 3 readlane -> 2 cndmask -> 32-bit shr+and+cvt -> 32 fmac (VMEM broadcast
// weights). Accumulation per (neuron,t): ascending (ky,kx,ic), ic innermost;
// bit=0 terms add +0.0 (exact no-op).
// ---------------------------------------------------------------------------
__global__ __launch_bounds__(256) void k_stage2E(const unsigned* __restrict__ z1p,
                                                 const float* __restrict__ wT2,
                                                 const unsigned* __restrict__ zbuf,
                                                 unsigned* __restrict__ z2p) {
  __shared__ float xp[4][20 * 97];
  int lane = threadIdx.x & 63;
  int wid  = threadIdx.x >> 6;
  int gw   = blockIdx.x * 4 + wid;             // wave index
  int q0 = 3 * gw, q1 = q0 + 1, q2 = q0 + 2;   // pixels: b*196 + y*14 + x
  bool vq0 = q0 < 25088, vq1 = q1 < 25088, vq2 = q2 < 25088;
  int b0 = q0 / 196, r0 = q0 % 196, y0 = r0 / 14, x0 = r0 % 14;
  int b1 = q1 / 196, r1 = q1 % 196, y1 = r1 / 14, x1 = r1 % 14;
  int b2 = q2 / 196, r2 = q2 % 196, y2 = r2 / 14, x2 = r2 % 14;

  int  li = lane & 31;
  bool lo = lane < 32;
  int  p  = lane / 20;             // 0..3 (p==3 idle in epilogue)
  int  tl = lane - p * 20;

  float acc[32];
#pragma unroll
  for (int o = 0; o < 32; ++o) acc[o] = 0.0f;

  // cell pointer computation (uniform per wave)
  auto cptr = [&](int ky, int kx, const unsigned*& c0, const unsigned*& c1,
                  const unsigned*& c2) {
    int y0k = y0 - 1 + ky, y1k = y1 - 1 + ky, y2k = y2 - 1 + ky;
    int x0k = x0 - 1 + kx, x1k = x1 - 1 + kx, x2k = x2 - 1 + kx;
    bool ok0 = vq0 && y0k >= 0 && y0k < 14 && x0k >= 0 && x0k < 14;
    bool ok1 = vq1 && y1k >= 0 && y1k < 14 && x1k >= 0 && x1k < 14;
    bool ok2 = vq2 && y2k >= 0 && y2k < 14 && x2k >= 0 && x2k < 14;
    c0 = ok0 ? (z1p + ((b0 * 14 + y0k) * 14 + x0k) * 32) : zbuf;
    c1 = ok1 ? (z1p + ((b1 * 14 + y1k) * 14 + x1k) * 32) : zbuf;
    c2 = ok2 ? (z1p + ((b2 * 14 + y2k) * 14 + x2k) * 32) : zbuf;
  };

  const unsigned *c0, *c1, *c2;
  cptr(0, 0, c0, c1, c2);
  unsigned va = (lo ? c0 : c1)[li];   // lanes 0-31: c0[li], 32-63: c1[li]
  unsigned vb = c2[li];

  for (int ky = 0; ky < 3; ++ky) {
    for (int kx = 0; kx < 3; ++kx) {
      // prefetch next cell
      unsigned va_n = 0u, vb_n = 0u;
      int nkx = kx + 1, nky = ky;
      if (nkx == 3) { nkx = 0; nky = ky + 1; }
      if (nky < 3) {
        const unsigned *n0, *n1, *n2;
        cptr(nky, nkx, n0, n1, n2);
        va_n = (lo ? n0 : n1)[li];
        vb_n = n2[li];
      }
      const float* wc = wT2 + (ky * 3 + kx) * 1024;
#pragma unroll 4
      for (int ic = 0; ic < 32; ++ic) {
        unsigned s0 = (unsigned)__builtin_amdgcn_readlane((int)va, ic);
        unsigned s1 = (unsigned)__builtin_amdgcn_readlane((int)va, 32 + ic);
        unsigned s2 = (unsigned)__builtin_amdgcn_readlane((int)vb, ic);
        unsigned mm = (p == 0) ? s0 : ((p == 1) ? s1 : s2);
        float bitf = (float)((mm >> tl) & 1u);
        const float* wrow = wc + ic * 32;
#pragma unroll
        for (int oc = 0; oc < 32; ++oc)
          acc[oc] = fmaf(wrow[oc], bitf, acc[oc]);
      }
      va = va_n; vb = vb_n;
    }
  }

  if (p < 3) {
#pragma unroll
    for (int oc = 0; oc < 32; ++oc)
      xp[wid][tl * 97 + p * 32 + oc] = acc[oc];
  }
  __syncthreads();

  for (int pass = 0; pass < 2; ++pass) {
    int n = lane + 64 * pass;
    if (n < 96) {
      int pp = n >> 5;
      int oc = n & 31;
      int q  = q0 + pp;
      if (q < 25088) {
        float v = 0.0f;
        int   r = 0;
        unsigned zm = 0u;
#pragma unroll
        for (int t = 0; t < 20; ++t) {
          float c = xp[wid][t * 97 + n];
          v += c;
          bool z = (v > THRF) && (r == 0);
          if (z) { v -= THRF; r = 3; } else if (r > 0) --r;
          if (z) zm |= 1u << t;
        }
        int b = q / 196, rr = q % 196, y = rr / 14, x = rr % 14;
        atomicOr(&z2p[b * 1568 + oc * 49 + (y >> 1) * 7 + (x >> 1)], zm);
      }
    }
  }
}

// ---------------------------------------------------------------------------
// Stage 3: dense currents + OUTPUT LIF fused (unchanged from rounds 9-17).
// ---------------------------------------------------------------------------
__global__ __launch_bounds__(256) void k_denseF(const unsigned* __restrict__ z2p,
                                                const float* __restrict__ WdT,
                                                float* __restrict__ out) {
  int lane = threadIdx.x & 63;
  int wid  = threadIdx.x >> 6;
  int gw   = blockIdx.x * 4 + wid;     // b*22 + og
  if (gw >= 128 * 22) return;
  int b  = gw / 22, og = gw % 22;
  int p  = lane / 20;                  // 0..3 (p==3 idle)
  int t  = lane - p * 20;
  int o  = og * 3 + p;
  bool live = (p < 3) && (o < 64);
  int osafe = live ? o : 63;
  const unsigned* zb = z2p + b * 1568;

  unsigned mA[16], mB[16];
  float    wA[16], wB[16];
#pragma unroll
  for (int u = 0; u < 16; ++u) { mA[u] = zb[u]; wA[u] = WdT[u * 64 + osafe]; }

  float acc = 0.0f;
  for (int f0 = 0; f0 < 1568; f0 += 32) {   // 1568 = 32*49
#pragma unroll
    for (int u = 0; u < 16; ++u) {
      int fn = f0 + 16 + u;
      mB[u] = zb[fn]; wB[u] = WdT[fn * 64 + osafe];
    }
#pragma unroll
    for (int u = 0; u < 16; ++u) {
      float bitf = (float)((mA[u] >> t) & 1u);
      acc = fmaf(wA[u], bitf, acc);
    }
    if (f0 + 32 < 1568) {
#pragma unroll
      for (int u = 0; u < 16; ++u) {
        int fn = f0 + 32 + u;
        mA[u] = zb[fn]; wA[u] = WdT[fn * 64 + osafe];
      }
    }
#pragma unroll
    for (int u = 0; u < 16; ++u) {
      float bitf = (float)((mB[u] >> t) & 1u);
      acc = fmaf(wB[u], bitf, acc);
    }
  }

  float v = 0.0f;
  int   r = 0;
  unsigned zm = 0u;
#pragma unroll
  for (int tt = 0; tt < 20; ++tt) {
    float c = __shfl(acc, p * 20 + tt, 64);  // p==3 lanes: garbage, discarded
    v += c;
    bool z = (v > THRF) && (r == 0);
    if (z) { v -= THRF; r = 3; } else if (r > 0) --r;
    if (z) zm |= 1u << tt;
  }
  if (live) out[(b * 20 + t) * 64 + o] = ((zm >> t) & 1u) ? 1.0f : 0.0f;
}

extern "C" void kernel_launch(void* const* d_in, const int* in_sizes, int n_in,
                              void* d_out, int out_size, void* d_ws, size_t ws_size,
                              hipStream_t stream) {
  const float* x  = (const float*)d_in[0];  // [128,1,28,28]
  const float* W1 = (const float*)d_in[1];  // [32,1,3,3]
  const float* W2 = (const float*)d_in[2];  // [32,32,3,3]
  const float* Wd = (const float*)d_in[3];  // [64,1568]
  float* out = (float*)d_out;               // [128,20,64]

  char* ws = (char*)d_ws;
  unsigned* mIn  = (unsigned*)ws;                      // 401408 B (dead after stage1)
  unsigned* z1p  = (unsigned*)(ws + 655360);           // 3211264 B (zeroed by k_pre)
  unsigned* z2p  = (unsigned*)(ws + 3866624);          // 802816 B (zeroed by k_pre)
  unsigned* zbuf = (unsigned*)(ws + 4669440);          // 128 B zeros (zeroed by k_pre)
  float*    w1T  = (float*)(ws + 4669568);             // 1152 B
  float*    w2T  = (float*)(ws + 4670720);             // 36864 B
  float*    WdT  = (float*)(ws + 4707584);             // 401408 B

  k_pre<<<dim3(392), dim3(256), 0, stream>>>(x, W1, W2, Wd, mIn, w1T, w2T, WdT, z1p);
  k_stage1M<<<dim3(25088), dim3(128), 0, stream>>>(mIn, w1T, z1p);
  k_stage2E<<<dim3(2091), dim3(256), 0, stream>>>(z1p, w2T, zbuf, z2p);
  k_denseF<<<dim3(704), dim3(256), 0, stream>>>(z2p, WdT, out);
}